// Round 4
// baseline (8007.513 us; speedup 1.0000x reference)
//
#include <hip/hip_runtime.h>
#include <cstdint>

typedef _Float16 half8 __attribute__((ext_vector_type(8)));
typedef _Float16 half4v __attribute__((ext_vector_type(4)));
typedef float floatx4 __attribute__((ext_vector_type(4)));
typedef unsigned long long u64;

__device__ __forceinline__ float sig_(float x) { return 1.f / (1.f + __expf(-x)); }
__device__ __forceinline__ float tanh_(float x) {
  x = fminf(15.f, fmaxf(-15.f, x));
  float e = __expf(2.f * x);
  return (e - 1.f) / (e + 1.f);
}

// ---------------- prep kernels ----------------
__global__ void cvt_x_kernel(const float* __restrict__ x, _Float16* __restrict__ xh, int n) {
  int i = (blockIdx.x * 256 + threadIdx.x) * 4;
  if (i < n) {
    const float4 v = *(const float4*)(x + i);
    half4v o = {(_Float16)v.x, (_Float16)v.y, (_Float16)v.z, (_Float16)v.w};
    *(half4v*)(xh + i) = o;
  }
}

// Permuted weights: row n of W*perm = w_{g}[u][:], u=n>>2, g=n&3.
__global__ void build_w_kernel(const float* w0, const float* w1, const float* w2, const float* w3,
                               const float* w4, const float* w5, const float* w6, const float* w7,
                               const float* b0, const float* b1, const float* b2, const float* b3,
                               _Float16* __restrict__ Wip, _Float16* __restrict__ Whp,
                               float* __restrict__ biasp) {
  int n = blockIdx.x;
  if (n < 8192) {
    const float* srcs[8] = {w0, w1, w2, w3, w4, w5, w6, w7};
    int which = n >> 12;
    int row = n & 4095;
    int u = row >> 2, g = row & 3;
    const float* s = srcs[which * 4 + g] + (size_t)u * 1024;
    _Float16* dst = (which ? Whp : Wip) + (size_t)row * 1024;
    int t = threadIdx.x * 4;
    float4 v = *(const float4*)(s + t);
    half4v o = {(_Float16)v.x, (_Float16)v.y, (_Float16)v.z, (_Float16)v.w};
    *(half4v*)(dst + t) = o;
  } else {
    const float* bs[4] = {b0, b1, b2, b3};
    for (int idx = threadIdx.x; idx < 4096; idx += 256)
      biasp[idx] = bs[idx & 3][idx >> 2];
  }
}

// h buffer layout (per 2048-B batch row r): two 1024-B K-chunks; within a chunk,
// unit k sits at byte ((k*2) + r*16) & 1023  (row-rotation kills LDS bank conflicts
// after lane-contiguous global_load_lds staging).
__global__ void init_h_kernel(const float* __restrict__ hx, char* __restrict__ hb0) {
  int i = blockIdx.x * 256 + threadIdx.x;
  if (i < 32768) {
    int r = i >> 9, j = i & 511;
    int c = j >> 8, xoff = (j & 255) * 4;
    int o = (xoff + r * 16) & 1023;
    unsigned short lo = __builtin_bit_cast(unsigned short, (_Float16)hx[r * 1024 + 2 * j]);
    unsigned short hi = __builtin_bit_cast(unsigned short, (_Float16)hx[r * 1024 + 2 * j + 1]);
    *(unsigned int*)(hb0 + (size_t)r * 2048 + c * 1024 + o) =
        (unsigned int)lo | ((unsigned int)hi << 16);
  }
}

__global__ void zero_flags_kernel(unsigned int* __restrict__ flags) {
  int i = blockIdx.x * 256 + threadIdx.x;
  if (i < 8192) flags[i] = 0u;
}

// ---------------- precompute GEMM ----------------
// G3 (fp16): [p(256)][t(512)][w(4)][kg(4)][ml(16)][r(4)] — rec kernel reads 1 u64/thread.
__global__ __launch_bounds__(256) void gemm_g_kernel(const _Float16* __restrict__ Xh,
                                                     const _Float16* __restrict__ Wp,
                                                     const float* __restrict__ biasp,
                                                     _Float16* __restrict__ G3) {
  __shared__ _Float16 Al[4][128][8];
  __shared__ _Float16 Bl[4][128][8];
  const int tid = threadIdx.x;
  const int w = tid >> 6, l = tid & 63;
  const int wm = (w >> 1) * 64, wn = (w & 1) * 64;
  const int ml = l & 15, kg = l >> 4;
  const int bm = blockIdx.x, bn = blockIdx.y;
  const int r0 = tid & 127, kc0 = tid >> 7;
  const int kc1 = kc0 + 2;
  const size_t arow0 = (size_t)(bm * 128 + r0) * 1024;
  const size_t brow0 = (size_t)(bn * 128 + r0) * 1024;
  floatx4 acc[4][4] = {};
  for (int kt = 0; kt < 1024; kt += 32) {
    __syncthreads();
    __builtin_amdgcn_global_load_lds(
        (const __attribute__((address_space(1))) unsigned int*)(Xh + arow0 + kt + kc0 * 8),
        (__attribute__((address_space(3))) unsigned int*)&Al[kc0][r0][0], 16, 0, 0);
    __builtin_amdgcn_global_load_lds(
        (const __attribute__((address_space(1))) unsigned int*)(Xh + arow0 + kt + kc1 * 8),
        (__attribute__((address_space(3))) unsigned int*)&Al[kc1][r0][0], 16, 0, 0);
    __builtin_amdgcn_global_load_lds(
        (const __attribute__((address_space(1))) unsigned int*)(Wp + brow0 + kt + kc0 * 8),
        (__attribute__((address_space(3))) unsigned int*)&Bl[kc0][r0][0], 16, 0, 0);
    __builtin_amdgcn_global_load_lds(
        (const __attribute__((address_space(1))) unsigned int*)(Wp + brow0 + kt + kc1 * 8),
        (__attribute__((address_space(3))) unsigned int*)&Bl[kc1][r0][0], 16, 0, 0);
    __syncthreads();
    half8 af[4], bf[4];
#pragma unroll
    for (int i = 0; i < 4; ++i) af[i] = *(const half8*)&Al[kg][wm + i * 16 + ml][0];
#pragma unroll
    for (int j = 0; j < 4; ++j) bf[j] = *(const half8*)&Bl[kg][wn + j * 16 + ml][0];
#pragma unroll
    for (int i = 0; i < 4; ++i)
#pragma unroll
      for (int j = 0; j < 4; ++j)
        acc[i][j] = __builtin_amdgcn_mfma_f32_16x16x32_f16(af[i], bf[j], acc[i][j], 0, 0, 0);
  }
  const int t = (bm * 128 + wm) >> 6;
#pragma unroll
  for (int j = 0; j < 4; ++j) {
    const int col = bn * 128 + wn + j * 16 + ml;
    const float bj = biasp[col];
    const int p = col >> 4;
#pragma unroll
    for (int i = 0; i < 4; ++i) {
      half4v pk = {(_Float16)(acc[i][j][0] + bj), (_Float16)(acc[i][j][1] + bj),
                   (_Float16)(acc[i][j][2] + bj), (_Float16)(acc[i][j][3] + bj)};
      *(half4v*)&G3[((size_t)p * 512 + t) * 1024 + i * 256 + kg * 64 + ml * 4] = pk;
    }
  }
}

// ---------------- persistent recurrent kernel ----------------
// 256 blocks x 4 waves. Block p owns units [4p,4p+4). Wh frags in registers.
// h consume: cached global_load_lds DMA into private wave slice, made coherent by a
// per-step agent acquire fence (buffer_inv) after the flag barrier. h publish:
// agent-atomic write-through stores (rotated layout). Flags: u32[256] contiguous,
// wave0-only poll.
__global__ __launch_bounds__(256, 1) void lstm_rec_kernel(
    const _Float16* __restrict__ G3, const _Float16* __restrict__ Whp,
    char* __restrict__ hbuf, const float* __restrict__ cx,
    float* __restrict__ out, unsigned int* __restrict__ flags) {
  const int p = blockIdx.x, tid = threadIdx.x;
  const int w = tid >> 6, l = tid & 63;
  const int ml = l & 15, kg = l >> 4;
  __shared__ char hl_[65536] __attribute__((aligned(16)));
  char* slice = hl_ + w * 16384;  // 16 rows x 1024 B (one K-chunk of this wave's batches)

  // persistent Wh B-fragments: lane (ml,kg) holds Whp[16p+ml][s*32+kg*8 .. +8]
  half8 wfr[32];
#pragma unroll
  for (int s = 0; s < 32; ++s)
    wfr[s] = *(const half8*)&Whp[(size_t)(16 * p + ml) * 1024 + s * 32 + kg * 8];

  const int bl = l >> 2, u = l & 3;
  const int bglob = 16 * w + bl, U = 4 * p + u;
  float c = cx[bglob * 1024 + U];
  const int rot = kg * 16 + ml * 16 + w * 256;  // global-row rotation + frag kg offset
  __syncthreads();

  u64 ginb = *(const u64*)&G3[((size_t)p * 512 + 0) * 1024 + w * 256 + kg * 64 + ml * 4];

  for (int t = 0; t < 512; ++t) {
    const char* hq = hbuf + (size_t)(t & 1) * 131072;
    char* hnq = hbuf + (size_t)((t & 1) ^ 1) * 131072;

    floatx4 acc[4] = {};
#pragma unroll
    for (int chunk = 0; chunk < 2; ++chunk) {
      // stage 16 rows x 1 KB via DMA (cached path -> L2 multicast within XCD)
#pragma unroll
      for (int r = 0; r < 16; ++r)
        __builtin_amdgcn_global_load_lds(
            (const __attribute__((address_space(1))) unsigned int*)(
                hq + (size_t)(16 * w + r) * 2048 + chunk * 1024 + l * 16),
            (__attribute__((address_space(3))) unsigned int*)(slice + r * 1024 + l * 16),
            16, 0, 0);
      __builtin_amdgcn_s_waitcnt(0x0F70);  // vmcnt(0)
      __builtin_amdgcn_wave_barrier();
#pragma unroll
      for (int s = 0; s < 16; ++s) {
        const int off = (s * 64 + rot) & 1023;
        half8 a = *(const half8*)(slice + ml * 1024 + off);
        acc[s & 3] =
            __builtin_amdgcn_mfma_f32_16x16x32_f16(a, wfr[chunk * 16 + s], acc[s & 3], 0, 0, 0);
      }
      if (chunk == 0) {
        __builtin_amdgcn_s_waitcnt(0xC07F);  // lgkmcnt(0): frag data in VGPRs
        __builtin_amdgcn_wave_barrier();
      }
    }
    floatx4 a4 = (acc[0] + acc[1]) + (acc[2] + acc[3]);

    // intra-wave gate exchange in own slice (chunk data fully consumed)
    union { u64 q; half4v h4; } gu; gu.q = ginb;
    float* glw = (float*)slice;
    __builtin_amdgcn_wave_barrier();
#pragma unroll
    for (int r = 0; r < 4; ++r)
      glw[(kg * 4 + r) * 20 + ml] = a4[r] + (float)gu.h4[r];
    __builtin_amdgcn_wave_barrier();
    const float4 g4 = *(const float4*)&glw[bl * 20 + u * 4];

    const float ig = sig_(g4.x), fg = sig_(g4.y);
    const float ag = tanh_(g4.z), og = sig_(g4.w);
    c = fg * c + ig * ag;
    const float h = og * tanh_(c);

    // publish h: pack 4 units -> one u64 agent write-through store (rotated layout)
    unsigned int mine = (unsigned int)__builtin_bit_cast(unsigned short, (_Float16)h);
    unsigned int pair = mine | (((unsigned int)__shfl_xor((int)mine, 1)) << 16);
    u64 quad = (u64)pair | ((u64)(unsigned int)__shfl_xor((int)pair, 2) << 32);
    if (u == 0) {
      const int hc = p >> 7;
      const int ho = (((p & 127) * 8) + bglob * 16) & 1023;
      __hip_atomic_store((u64*)(hnq + (size_t)bglob * 2048 + hc * 1024 + ho), quad,
                         __ATOMIC_RELAXED, __HIP_MEMORY_SCOPE_AGENT);
    }

    if (t == 511) {
      out[(size_t)t * 65536 + bglob * 1024 + U] = h;
      out[(size_t)33554432 + bglob * 1024 + U] = h;  // hy
      out[(size_t)33619968 + bglob * 1024 + U] = c;  // cy
      break;
    }

    // ---- grid barrier ----
    __builtin_amdgcn_s_waitcnt(0x0F70);  // publish acked at coherence point
    __syncthreads();
    if (tid == 0)
      __hip_atomic_store(&flags[p], (unsigned)(t + 1), __ATOMIC_RELAXED,
                         __HIP_MEMORY_SCOPE_AGENT);
    // prefetch next step's G slice (immutable data; latency hides under the poll)
    u64 gin_next =
        *(const u64*)&G3[((size_t)p * 512 + (t + 1)) * 1024 + w * 256 + kg * 64 + ml * 4];
    out[(size_t)t * 65536 + bglob * 1024 + U] = h;  // off the critical path
    if (w == 0) {
      const unsigned tgt = (unsigned)(t + 1);
      const u64* fq = (const u64*)flags;
      for (;;) {
        u64 q0 = __hip_atomic_load(&fq[l], __ATOMIC_RELAXED, __HIP_MEMORY_SCOPE_AGENT);
        u64 q1 = __hip_atomic_load(&fq[64 + l], __ATOMIC_RELAXED, __HIP_MEMORY_SCOPE_AGENT);
        int ok = ((unsigned)q0 >= tgt) & ((unsigned)(q0 >> 32) >= tgt) &
                 ((unsigned)q1 >= tgt) & ((unsigned)(q1 >> 32) >= tgt);
        if (__all(ok)) break;
        __builtin_amdgcn_s_sleep(2);
      }
    }
    __syncthreads();
    __builtin_amdgcn_fence(__ATOMIC_ACQUIRE, "agent");  // buffer_inv: L1/L2 drop stale h
    ginb = gin_next;
    asm volatile("" ::: "memory");
  }
}

// ---------------- launch ----------------
extern "C" void kernel_launch(void* const* d_in, const int* in_sizes, int n_in,
                              void* d_out, int out_size, void* d_ws, size_t ws_size,
                              hipStream_t stream) {
  const float* x    = (const float*)d_in[0];
  const float* hx   = (const float*)d_in[1];
  const float* cxp  = (const float*)d_in[2];
  const float* w_ii = (const float*)d_in[3];
  const float* w_fi = (const float*)d_in[4];
  const float* w_ai = (const float*)d_in[5];
  const float* w_oi = (const float*)d_in[6];
  const float* w_ih = (const float*)d_in[7];
  const float* w_fh = (const float*)d_in[8];
  const float* w_ah = (const float*)d_in[9];
  const float* w_oh = (const float*)d_in[10];
  const float* b_i  = (const float*)d_in[11];
  const float* b_f  = (const float*)d_in[12];
  const float* b_a  = (const float*)d_in[13];
  const float* b_o  = (const float*)d_in[14];
  float* out = (float*)d_out;

  char* ws = (char*)d_ws;
  _Float16* Xh        = (_Float16*)(ws);                 // 64 MB (dead after gemm_g)
  unsigned int* flags = (unsigned int*)(ws);             // 1 KB, aliases Xh (zeroed post-gemm)
  _Float16* Wip       = (_Float16*)(ws + 67108864);      // 8 MB
  _Float16* Whp       = (_Float16*)(ws + 75497472);      // 8 MB
  float* biasp        = (float*)(ws + 83886080);         // 16 KB
  char* hbuf          = (char*)(ws + 83902464);          // 256 KB (2 rotated buffers)
  _Float16* G3        = (_Float16*)(ws + 84164864);      // 256 MB
  if (ws_size < (size_t)84164864 + 268435456) return;

  cvt_x_kernel<<<32768, 256, 0, stream>>>(x, Xh, 33554432);
  build_w_kernel<<<8193, 256, 0, stream>>>(w_ii, w_fi, w_ai, w_oi, w_ih, w_fh, w_ah, w_oh,
                                           b_i, b_f, b_a, b_o, Wip, Whp, biasp);
  init_h_kernel<<<128, 256, 0, stream>>>(hx, hbuf);
  gemm_g_kernel<<<dim3(256, 32), 256, 0, stream>>>(Xh, Wip, biasp, G3);
  zero_flags_kernel<<<32, 256, 0, stream>>>(flags);
  lstm_rec_kernel<<<256, 256, 0, stream>>>(G3, Whp, hbuf, cxp, out, flags);
}